// Round 5
// baseline (453.838 us; speedup 1.0000x reference)
//
#include <hip/hip_runtime.h>
#include <hip/hip_bf16.h>

// Shapes
#define B_   128
#define S_   400
#define H_   512
#define V_   50257
#define VX_  50307
#define NBN_ 1571   // ceil(V/32) vocab col-panels

// Output offsets (floats, concatenated in return order)
#define OFF_FINAL 0
#define OFF_PGEN  6439296
#define OFF_ATTN  6439424
#define OFF_COV   6490624
#define OFF_H1    6541824
#define OFF_C1    6607360
#define OFF_DEC   6672896

typedef __attribute__((ext_vector_type(8))) short bf16x8;
typedef __attribute__((ext_vector_type(4))) float f32x4;

static __device__ __forceinline__ float sigmoid_f(float x) {
    return 1.0f / (1.0f + __expf(-x));
}
static __device__ __forceinline__ float tanh_f(float x) {
    return 1.0f - 2.0f / (__expf(2.0f * x) + 1.0f);
}
// f32x2 -> packed bf16x2 (RNE) — v_cvt_pk_bf16_f32 on gfx950
static __device__ __forceinline__ unsigned int pk2(float x, float y) {
    union { __hip_bfloat162 h; unsigned int u; } cv;
    cv.h = __float22bfloat162_rn(make_float2(x, y));
    return cv.u;
}

// Zero: o_final (scatter target), split-K accum region of ws, o_dec, w_ctx,
// p_gen accumulator.
__global__ __launch_bounds__(256) void zero_ws(
    float4* __restrict__ fin4, float4* __restrict__ ws4,
    float4* __restrict__ dec4, float4* __restrict__ ctx4,
    float4* __restrict__ pga4)
{
    const int i = blockIdx.x * 256 + threadIdx.x;
    const float4 z = make_float4(0.f, 0.f, 0.f, 0.f);
    if (i < 1609824) fin4[i] = z;   // 128*50307/4
    if (i < 98304)   ws4[i] = z;    // w_x + w_decfea + w_gates
    if (i < 16384)   dec4[i] = z;
    if (i < 16384)   ctx4[i] = z;
    if (i < 32)      pga4[i] = z;
}

// ---------------------------------------------------------------------------
// Generic small GEMM: C[128 x N] (+)= A1@W1^T (+ A2@W2^T) + bias1.
// Split-K via grid.y with atomic epilogue; optional fused p_gen dot.
// ---------------------------------------------------------------------------
template <int NT>
__global__ __launch_bounds__(256) void gemm_mfma(
    const float* __restrict__ A1, const float* __restrict__ W1, int ldw1, int kwo1,
    const float* __restrict__ A2, const float* __restrict__ W2, int ldw2, int kwo2,
    const float* __restrict__ bias1,
    float* __restrict__ C, int N,
    const float* __restrict__ wpg, float* __restrict__ pgen_acc)
{
    __shared__ __align__(16) unsigned short As[128 * 40];
    __shared__ __align__(16) unsigned short Ws[NT * 16 * 40];
    const int tid  = threadIdx.x;
    const int bn0  = blockIdx.x * (NT * 16);
    const int lane = tid & 63;
    const int wv   = tid >> 6;
    const int quad = lane >> 4;
    const int col  = lane & 15;

    f32x4 acc[2][NT];
#pragma unroll
    for (int i = 0; i < 2; ++i)
#pragma unroll
        for (int j = 0; j < NT; ++j) acc[i][j] = (f32x4){0.f, 0.f, 0.f, 0.f};

    const int ar = tid >> 1;
    const int ac = (tid & 1) << 4;
    const int wr = (NT == 8) ? (tid >> 1) : (tid >> 2);
    const int wc = (NT == 8) ? ((tid & 1) << 4) : ((tid & 3) << 3);
    const int wrg = (bn0 + wr < N) ? (bn0 + wr) : (N - 1);

    const int Ktot = (A2 != nullptr) ? 1024 : 512;
    const int KC   = Ktot / gridDim.y;
    const int kg0  = blockIdx.y * KC;
    const int nsteps = KC >> 5;

    const float* ApB[2];
    const float* WpB[2];
    ApB[0] = A1 + (long)ar * 512 + ac;
    WpB[0] = W1 + (long)wrg * ldw1 + kwo1 + wc;
    ApB[1] = A2 ? (A2 + (long)ar * 512 + ac) : ApB[0];
    WpB[1] = W2 ? (W2 + (long)wrg * ldw2 + kwo2 + wc) : WpB[0];

    float4 aC[4], wC[NT / 2], aN[4], wN[NT / 2];

    auto fetch = [&](int s, float4* a, float4* w) {
        const int kg = kg0 + (s << 5);
        const int ph = kg >> 9;
        const int k0 = kg & 511;
        const float* Ap = ApB[ph] + k0;
        const float* Wp = WpB[ph] + k0;
#pragma unroll
        for (int i = 0; i < 4; ++i) a[i] = *(const float4*)(Ap + i * 4);
#pragma unroll
        for (int i = 0; i < NT / 2; ++i) w[i] = *(const float4*)(Wp + i * 4);
    };

    fetch(0, aC, wC);
    for (int s = 0; s < nsteps; ++s) {
        __syncthreads();
        uint4* apd = (uint4*)&As[ar * 40 + ac];
        apd[0] = make_uint4(pk2(aC[0].x, aC[0].y), pk2(aC[0].z, aC[0].w),
                            pk2(aC[1].x, aC[1].y), pk2(aC[1].z, aC[1].w));
        apd[1] = make_uint4(pk2(aC[2].x, aC[2].y), pk2(aC[2].z, aC[2].w),
                            pk2(aC[3].x, aC[3].y), pk2(aC[3].z, aC[3].w));
        uint4* wpd = (uint4*)&Ws[wr * 40 + wc];
        wpd[0] = make_uint4(pk2(wC[0].x, wC[0].y), pk2(wC[0].z, wC[0].w),
                            pk2(wC[1].x, wC[1].y), pk2(wC[1].z, wC[1].w));
        if (NT == 8)
            wpd[1] = make_uint4(pk2(wC[2].x, wC[2].y), pk2(wC[2].z, wC[2].w),
                                pk2(wC[3].x, wC[3].y), pk2(wC[3].z, wC[3].w));
        __syncthreads();

        if (s + 1 < nsteps) fetch(s + 1, aN, wN);

        const bf16x8 aF0 = *(const bf16x8*)&As[(wv * 32 + col) * 40 + quad * 8];
        const bf16x8 aF1 = *(const bf16x8*)&As[(wv * 32 + 16 + col) * 40 + quad * 8];
#pragma unroll
        for (int ni = 0; ni < NT; ++ni) {
            const bf16x8 bF = *(const bf16x8*)&Ws[(ni * 16 + col) * 40 + quad * 8];
            acc[0][ni] = __builtin_amdgcn_mfma_f32_16x16x32_bf16(aF0, bF, acc[0][ni], 0, 0, 0);
            acc[1][ni] = __builtin_amdgcn_mfma_f32_16x16x32_bf16(aF1, bF, acc[1][ni], 0, 0, 0);
        }
#pragma unroll
        for (int i = 0; i < 4; ++i) aC[i] = aN[i];
#pragma unroll
        for (int i = 0; i < NT / 2; ++i) wC[i] = wN[i];
    }

    const bool split = (gridDim.y > 1);
    const bool addb  = (!split) || (blockIdx.y == 0);

    float pgp[2][4];
#pragma unroll
    for (int i = 0; i < 2; ++i)
#pragma unroll
        for (int r = 0; r < 4; ++r) pgp[i][r] = 0.f;

#pragma unroll
    for (int mi = 0; mi < 2; ++mi) {
#pragma unroll
        for (int ni = 0; ni < NT; ++ni) {
            const int n = bn0 + ni * 16 + col;
            if (n < N) {
                const float bv = addb ? bias1[n] : 0.f;
                const float wpv = wpg ? wpg[n] : 0.f;
#pragma unroll
                for (int r = 0; r < 4; ++r) {
                    const int m = wv * 32 + mi * 16 + quad * 4 + r;
                    const float v = acc[mi][ni][r] + bv;
                    if (split) atomicAdd(&C[(long)m * N + n], v);
                    else       C[(long)m * N + n] = v;
                    pgp[mi][r] += v * wpv;
                }
            }
        }
    }
    if (wpg) {
#pragma unroll
        for (int mi = 0; mi < 2; ++mi)
#pragma unroll
            for (int r = 0; r < 4; ++r) {
                float v = pgp[mi][r];
                v += __shfl_xor(v, 1); v += __shfl_xor(v, 2);
                v += __shfl_xor(v, 4); v += __shfl_xor(v, 8);
                if (col == 0) {
                    const int m = wv * 32 + mi * 16 + quad * 4 + r;
                    atomicAdd(&pgen_acc[m], v);
                }
            }
    }
}

// ---------------------------------------------------------------------------
// Pack A (= dec_out, 128x512 f32) into MFMA-fragment-ordered bf16:
// unit u = ((sl*8+mt)*4+q)*16+c  holds A[mt*16+c][sl*32+q*8 .. +8] (16B).
// ---------------------------------------------------------------------------
__global__ __launch_bounds__(256) void pack_a(
    const float* __restrict__ A, unsigned short* __restrict__ Apk)
{
    const int u  = blockIdx.x * 256 + threadIdx.x;  // 8192 units
    const int c  = u & 15;
    const int q  = (u >> 4) & 3;
    const int mt = (u >> 6) & 7;
    const int sl = u >> 9;
    const float* src = A + (long)(mt * 16 + c) * 512 + sl * 32 + q * 8;
    const float4 x = *(const float4*)src;
    const float4 y = *(const float4*)(src + 4);
    *(uint4*)(Apk + (long)u * 8) = make_uint4(pk2(x.x, x.y), pk2(x.z, x.w),
                                              pk2(y.x, y.y), pk2(y.z, y.w));
}

// ---------------------------------------------------------------------------
// Vocab GEMM v5: C[128 x N] = A @ W^T + bias, fused raw exp-sum partials
// (softmax shift-invariance: logits are O(1) for this model, no max needed).
// Block = 32 cols x 128 rows; 32KB LDS -> 5 blocks/CU. Wave w owns rows
// [32w,32w+32). A-fragments from packed L2-hot Apk with 4-deep prefetch.
// ---------------------------------------------------------------------------
__global__ __launch_bounds__(256, 5) void vocab_gemm(
    const unsigned short* __restrict__ Apk, const float* __restrict__ W,
    const float* __restrict__ bias, float* __restrict__ C, int N,
    float* __restrict__ ps, int nbn)
{
    __shared__ __align__(16) unsigned short Ws[32 * 512];  // 32 KB
    const int tid  = threadIdx.x;
    const int lane = tid & 63;
    const int w    = tid >> 6;
    const int quad = lane >> 4;
    const int c    = lane & 15;
    const int nb   = blockIdx.x;

    // ---- stage W[nb*32 .. +32)[0..512) -> bf16 LDS, swizzled (16B gran) ----
#pragma unroll
    for (int i = 0; i < 8; ++i) {
        const int r  = i * 4 + w;                       // local row 0..31
        const int rg = (nb * 32 + r < N) ? (nb * 32 + r) : (N - 1);
        const float* src = W + (long)rg * 512 + (lane << 3);
        const float4 x = *(const float4*)src;
        const float4 y = *(const float4*)(src + 4);
        const int a16 = (r << 6) + (lane ^ (r & 7));    // 16B-unit index
        *(uint4*)&Ws[a16 << 3] = make_uint4(pk2(x.x, x.y), pk2(x.z, x.w),
                                            pk2(y.x, y.y), pk2(y.z, y.w));
    }

    f32x4 acc[2][2];   // [mi][nj]
#pragma unroll
    for (int mi = 0; mi < 2; ++mi)
#pragma unroll
        for (int nj = 0; nj < 2; ++nj) acc[mi][nj] = (f32x4){0.f, 0.f, 0.f, 0.f};

    bf16x8 aP0[2], aP1[2], aP2[2], aP3[2];
    auto loadA = [&](int sl, bf16x8* dst) {
#pragma unroll
        for (int mi = 0; mi < 2; ++mi) {
            const int u = ((sl * 8 + (w * 2 + mi)) * 4 + quad) * 16 + c;
            dst[mi] = *(const bf16x8*)(Apk + (long)u * 8);
        }
    };
    loadA(0, aP0); loadA(1, aP1); loadA(2, aP2); loadA(3, aP3);
    __syncthreads();

#pragma unroll
    for (int sl = 0; sl < 16; ++sl) {
        bf16x8* cur = ((sl & 3) == 0) ? aP0 : ((sl & 3) == 1) ? aP1
                    : ((sl & 3) == 2) ? aP2 : aP3;
        const int uk = ((sl << 2) + quad) ^ (c & 7);
        const bf16x8 bF0 = *(const bf16x8*)&Ws[((c << 6) + uk) << 3];
        const bf16x8 bF1 = *(const bf16x8*)&Ws[((((16 + c)) << 6) + uk) << 3];
        acc[0][0] = __builtin_amdgcn_mfma_f32_16x16x32_bf16(cur[0], bF0, acc[0][0], 0, 0, 0);
        acc[0][1] = __builtin_amdgcn_mfma_f32_16x16x32_bf16(cur[0], bF1, acc[0][1], 0, 0, 0);
        acc[1][0] = __builtin_amdgcn_mfma_f32_16x16x32_bf16(cur[1], bF0, acc[1][0], 0, 0, 0);
        acc[1][1] = __builtin_amdgcn_mfma_f32_16x16x32_bf16(cur[1], bF1, acc[1][1], 0, 0, 0);
        if (sl + 4 < 16) loadA(sl + 4, cur);
    }

    // ---- epilogue: store logits + in-wave per-row raw exp-sums ----
    const int n0 = nb * 32 + c;
    const int n1 = nb * 32 + 16 + c;
    const bool ok0 = (n0 < N), ok1 = (n1 < N);
    const float bv0 = bias[ok0 ? n0 : (N - 1)];
    const float bv1 = bias[ok1 ? n1 : (N - 1)];
#pragma unroll
    for (int mi = 0; mi < 2; ++mi) {
#pragma unroll
        for (int r = 0; r < 4; ++r) {
            const int m = w * 32 + mi * 16 + quad * 4 + r;
            const float v0 = acc[mi][0][r] + bv0;
            const float v1 = acc[mi][1][r] + bv1;
            if (ok0) C[(long)m * N + n0] = v0;
            if (ok1) C[(long)m * N + n1] = v1;
            float sv = (ok0 ? __expf(v0) : 0.f) + (ok1 ? __expf(v1) : 0.f);
            sv += __shfl_xor(sv, 1); sv += __shfl_xor(sv, 2);
            sv += __shfl_xor(sv, 4); sv += __shfl_xor(sv, 8);
            if (c == 0) ps[(long)m * nbn + nb] = sv;
        }
    }
}

// Merge exp-sum partials -> Srow; compute p_gen; scatter-add copy dist into
// the pre-zeroed final buffer. grid = 128 rows.
__global__ __launch_bounds__(256) void merge_scatter(
    const float* __restrict__ ps, int nblk,
    const float* __restrict__ pgen_acc, const float* __restrict__ bpg,
    const int* __restrict__ ids, const float* __restrict__ attn,
    float* __restrict__ Srow, float* __restrict__ o_pgen,
    float* __restrict__ final)
{
    __shared__ float sred[4];
    __shared__ float sPG;
    const int b = blockIdx.x, tid = threadIdx.x;
    const float* psb = ps + (long)b * nblk;

    float s = 0.f;
    for (int i = tid; i < nblk; i += 256) s += psb[i];
#pragma unroll
    for (int off = 32; off > 0; off >>= 1) s += __shfl_down(s, off);
    if ((tid & 63) == 0) sred[tid >> 6] = s;
    __syncthreads();
    if (tid == 0) {
        Srow[b] = sred[0] + sred[1] + sred[2] + sred[3];
        const float pg = sigmoid_f(pgen_acc[b] + bpg[0]);
        o_pgen[b] = pg;
        sPG = pg;
    }
    __syncthreads();
    const float omp = 1.0f - sPG;
    for (int sidx = tid; sidx < 400; sidx += 256) {
        const float v = omp * attn[b * 400 + sidx];
        atomicAdd(final + (long)b * VX_ + ids[b * 400 + sidx], v);
    }
}

// Elementwise LSTM cell over the accumulated gates buffer [128 x 2048]
// (i,f,g,o column-stacked). b_ih was added by the gates GEMM; add b_hh here.
__global__ __launch_bounds__(256) void lstm_cell(
    const float* __restrict__ gates, const float* __restrict__ bhh,
    const float* __restrict__ c0,
    float* __restrict__ h1, float* __restrict__ c1)
{
    const int idx = blockIdx.x * 256 + threadIdx.x;  // 65536 = 128*512
    const int m = idx >> 9;
    const int h = idx & 511;
    const float* g = gates + (long)m * 2048;
    const float iv = sigmoid_f(g[h]        + bhh[h]);
    const float fv = sigmoid_f(g[512 + h]  + bhh[512 + h]);
    const float gv = tanh_f   (g[1024 + h] + bhh[1024 + h]);
    const float ov = sigmoid_f(g[1536 + h] + bhh[1536 + h]);
    const float c = fv * c0[idx] + iv * gv;
    c1[idx] = c;
    h1[idx] = ov * tanh_f(c);
}

// e[b,s] = sum_h tanh(sf[b,s,h] + dec_fea[b,h] + wc*cov[b,s]) * v_att[h]
__global__ __launch_bounds__(256) void attn_scores(
    const float* __restrict__ sfeat, const float* __restrict__ decfea,
    const float* __restrict__ cov, const float* __restrict__ wc,
    const float* __restrict__ vatt, float* __restrict__ e)
{
    const int lane = threadIdx.x & 63;
    const int pair = blockIdx.x * 4 + (threadIdx.x >> 6);  // b*400+s
    const int b = pair / 400;
    const float cc = wc[0] * cov[pair];
    const float* sp = sfeat + ((long)pair << 9) + (lane << 3);
    const float* dp = decfea + (b << 9) + (lane << 3);
    const float* vp = vatt + (lane << 3);
    const float4 s0 = *(const float4*)sp, s1 = *(const float4*)(sp + 4);
    const float4 d0 = *(const float4*)dp, d1 = *(const float4*)(dp + 4);
    const float4 v0 = *(const float4*)vp, v1 = *(const float4*)(vp + 4);
    float acc = tanh_f(s0.x + d0.x + cc) * v0.x
              + tanh_f(s0.y + d0.y + cc) * v0.y
              + tanh_f(s0.z + d0.z + cc) * v0.z
              + tanh_f(s0.w + d0.w + cc) * v0.w
              + tanh_f(s1.x + d1.x + cc) * v1.x
              + tanh_f(s1.y + d1.y + cc) * v1.y
              + tanh_f(s1.z + d1.z + cc) * v1.z
              + tanh_f(s1.w + d1.w + cc) * v1.w;
#pragma unroll
    for (int off = 32; off > 0; off >>= 1) acc += __shfl_down(acc, off);
    if (lane == 0) e[pair] = acc;
}

// Fused masked softmax + coverage update + ctx partial accumulation.
// grid 512: block (b, chunk) recomputes row stats (L2-hot 3.2KB), writes
// attn/covnew for its 100-s chunk, accumulates ctx partial via atomicAdd.
__global__ __launch_bounds__(256) void softmax_ctx(
    const float* __restrict__ e, const float* __restrict__ mask,
    const float* __restrict__ cov, const float* __restrict__ states,
    float* __restrict__ attn, float* __restrict__ covnew,
    float* __restrict__ ctx)
{
    __shared__ float sm[4], sps[4], spms[4];
    __shared__ float s_attn[100];
    const int bx = blockIdx.x;
    const int b = bx >> 2, chunk = bx & 3;
    const int tid = threadIdx.x;

    float vals[2], msk[2];
    float m = -3.0e38f;
#pragma unroll
    for (int it = 0; it < 2; ++it) {
        const int s = tid + (it << 8);
        float mk = 0.f, v = -3.0e38f;
        if (s < 400) {
            mk = mask[b * 400 + s];
            v = (mk > 0.f) ? e[b * 400 + s] : -1.0e9f;
        }
        vals[it] = v; msk[it] = mk;
        m = fmaxf(m, v);
    }
#pragma unroll
    for (int off = 32; off > 0; off >>= 1) m = fmaxf(m, __shfl_down(m, off));
    if ((tid & 63) == 0) sm[tid >> 6] = m;
    __syncthreads();
    const float M = fmaxf(fmaxf(sm[0], sm[1]), fmaxf(sm[2], sm[3]));

    float sp = 0.f, spm = 0.f;
#pragma unroll
    for (int it = 0; it < 2; ++it) {
        const int s = tid + (it << 8);
        float pv = 0.f;
        if (s < 400) pv = __expf(vals[it] - M);
        sp += pv; spm += pv * msk[it];
    }
#pragma unroll
    for (int off = 32; off > 0; off >>= 1) {
        sp += __shfl_down(sp, off);
        spm += __shfl_down(spm, off);
    }
    if ((tid & 63) == 0) { sps[tid >> 6] = sp; spms[tid >> 6] = spm; }
    __syncthreads();
    const float SP = sps[0] + sps[1] + sps[2] + sps[3];
    const float SPM = spms[0] + spms[1] + spms[2] + spms[3];
    const float inv = 1.0f / (SPM + 1e-12f * SP);

    if (tid < 100) {
        const int s = chunk * 100 + tid;
        const float mk = mask[b * 400 + s];
        const float pv = (mk > 0.f) ? __expf(e[b * 400 + s] - M) : 0.f;
        const float a = pv * mk * inv;
        attn[b * 400 + s] = a;
        covnew[b * 400 + s] = cov[b * 400 + s] + a;
        s_attn[tid] = a;
    }
    __syncthreads();

    const int c = tid & 127;
    const int sh = tid >> 7;
    const float* base = states + (long)b * 400 * 512 + (long)chunk * 100 * 512;
    float4 acc = make_float4(0.f, 0.f, 0.f, 0.f);
    for (int i = 0; i < 50; ++i) {
        const int sl = sh + (i << 1);
        const float a = s_attn[sl];
        const float4 st = *(const float4*)(base + (long)sl * 512 + (c << 2));
        acc.x = fmaf(a, st.x, acc.x);
        acc.y = fmaf(a, st.y, acc.y);
        acc.z = fmaf(a, st.z, acc.z);
        acc.w = fmaf(a, st.w, acc.w);
    }
    float* cp = ctx + (b << 9) + (c << 2);
    atomicAdd(cp + 0, acc.x);
    atomicAdd(cp + 1, acc.y);
    atomicAdd(cp + 2, acc.z);
    atomicAdd(cp + 3, acc.w);
}

// final[b, v<V] += p_gen*exp(logit)/S  (scatter contributions already in
// place; v>=V keeps scatter-only value).
__global__ __launch_bounds__(256) void final_write(
    const float* __restrict__ logits, const float* __restrict__ Srow,
    const float* __restrict__ o_pgen, float* __restrict__ final)
{
    const int b = blockIdx.y;
    const int tid = threadIdx.x;
    const float sc = o_pgen[b] / Srow[b];
    const int v0 = (blockIdx.x * 256 + tid) << 2;
    if (v0 >= VX_) return;
    const float* row = logits + (long)b * V_;
    float* out = final + (long)b * VX_ + v0;
#pragma unroll
    for (int j = 0; j < 4; ++j) {
        const int v = v0 + j;
        if (v < V_) out[j] += __expf(row[v]) * sc;
    }
}

extern "C" void kernel_launch(void* const* d_in, const int* in_sizes, int n_in,
                              void* d_out, int out_size, void* d_ws, size_t ws_size,
                              hipStream_t stream)
{
    const float* input_emb  = (const float*)d_in[0];
    const float* input_feed = (const float*)d_in[1];
    const float* hidden     = (const float*)d_in[2];
    const float* context    = (const float*)d_in[3];
    const float* states     = (const float*)d_in[4];
    const float* sfeat      = (const float*)d_in[5];
    const float* mask       = (const float*)d_in[6];
    const float* cov        = (const float*)d_in[7];
    const int*   src_ids    = (const int*)d_in[8];
    const float* W_ic  = (const float*)d_in[9];
    const float* b_ic  = (const float*)d_in[10];
    const float* W_ih  = (const float*)d_in[11];
    const float* W_hh  = (const float*)d_in[12];
    const float* b_ih  = (const float*)d_in[13];
    const float* b_hh  = (const float*)d_in[14];
    const float* W_dec = (const float*)d_in[15];
    const float* b_att = (const float*)d_in[16];
    const float* v_att = (const float*)d_in[17];
    const float* w_c   = (const float*)d_in[18];
    const float* W_out = (const float*)d_in[19];
    const float* b_out = (const float*)d_in[20];
    const float* W_pg  = (const float*)d_in[21];
    const float* b_pg  = (const float*)d_in[22];
    const float* W_v   = (const float*)d_in[23];
    const float* b_v   = (const float*)d_in[24];

    float* out = (float*)d_out;
    float* o_final = out + OFF_FINAL;
    float* o_pgen  = out + OFF_PGEN;
    float* o_attn  = out + OFF_ATTN;
    float* o_cov   = out + OFF_COV;
    float* o_h1    = out + OFF_H1;
    float* o_c1    = out + OFF_C1;
    float* o_dec   = out + OFF_DEC;

    // ws layout (floats). Early phase: w_x [0,65536) w_decfea [65536,131072)
    // w_gates [131072,393216) w_e [393344,444544) w_ctx [444544,510080).
    // Vocab phase (after those die): w_ps [0,201088).
    // Stable tail: w_logits [510080,6942976) w_apk [6942976,6975744)
    // Srow/pga at 6975744/6976000.
    float* ws = (float*)d_ws;
    float* w_x      = ws;
    float* w_decfea = ws + 65536;
    float* w_gates  = ws + 131072;
    float* w_ps     = ws;             // reuses dead early-phase region
    float* w_e      = ws + 393344;
    float* w_ctx    = ws + 444544;
    float* w_logits = ws + 510080;
    unsigned short* w_apk = (unsigned short*)(ws + 6942976);
    float* w_Srow   = ws + 6975744;
    float* w_pga    = ws + 6976000;

    const dim3 blk(256);
    // zero o_final (scatter target), split-K accums, o_dec, w_ctx, pga
    zero_ws<<<6290, blk, 0, stream>>>((float4*)o_final, (float4*)ws,
                                      (float4*)o_dec, (float4*)w_ctx,
                                      (float4*)w_pga);
    // x = [emb, feed] @ W_ic^T + b_ic   (split-K: 8 n-tiles x 8 chunks)
    gemm_mfma<4><<<dim3(8, 8), blk, 0, stream>>>(
        input_emb, W_ic, 1024, 0, input_feed, W_ic, 1024, 512,
        b_ic, w_x, 512, nullptr, nullptr);
    // gates = x @ W_ih^T + h0 @ W_hh^T + b_ih   (split-K: 32 n-tiles x 4 chunks)
    gemm_mfma<4><<<dim3(32, 4), blk, 0, stream>>>(
        w_x, W_ih, 512, 0, hidden, W_hh, 512, 0,
        b_ih, w_gates, 2048, nullptr, nullptr);
    // LSTM cell (adds b_hh) -> h1, c1
    lstm_cell<<<256, blk, 0, stream>>>(w_gates, b_hh, context, o_h1, o_c1);
    // dec_fea = h1 @ W_dec^T + b_att   (split-K: 8 x 4)
    gemm_mfma<4><<<dim3(8, 4), blk, 0, stream>>>(
        o_h1, W_dec, 512, 0, nullptr, nullptr, 0, 0,
        b_att, w_decfea, 512, nullptr, nullptr);
    // attention scores
    attn_scores<<<12800, blk, 0, stream>>>(sfeat, w_decfea, cov, w_c, v_att, w_e);
    // fused softmax + coverage + ctx
    softmax_ctx<<<512, blk, 0, stream>>>(w_e, mask, cov, states,
                                         o_attn, o_cov, w_ctx);
    // dec_out = [h1, ctx] @ W_out^T + b_out   (split-K 8 x 8, fused p_gen dot)
    gemm_mfma<4><<<dim3(8, 8), blk, 0, stream>>>(
        o_h1, W_out, 1024, 0, w_ctx, W_out, 1024, 512,
        b_out, o_dec, 512, W_pg, w_pga);
    // pack dec_out into MFMA-fragment bf16 layout (L2-resident)
    pack_a<<<32, blk, 0, stream>>>(o_dec, w_apk);
    // vocab logits + fused raw exp-sum partials (1571 blocks, 5/CU)
    vocab_gemm<<<NBN_, blk, 0, stream>>>(
        w_apk, W_v, b_v, w_logits, V_, w_ps, NBN_);
    // merge exp-sums -> Srow; p_gen; scatter copy-dist into zeroed final
    merge_scatter<<<128, blk, 0, stream>>>(w_ps, NBN_, w_pga, b_pg,
                                           src_ids, o_attn,
                                           w_Srow, o_pgen, o_final);
    // vocab dist: final += pg * exp(logit) / S
    final_write<<<dim3(50, 128), blk, 0, stream>>>(w_logits, w_Srow,
                                                   o_pgen, o_final);
}

// Round 6
// 432.245 us; speedup vs baseline: 1.0500x; 1.0500x over previous
//
#include <hip/hip_runtime.h>
#include <hip/hip_bf16.h>

// Shapes
#define B_   128
#define S_   400
#define H_   512
#define V_   50257
#define VX_  50307
#define NBN_ 1571   // ceil(V/32) vocab col-panels
#define ELD_ 50264  // elogits row stride (ushorts), mult of 8 for aligned stores

// Output offsets (floats, concatenated in return order)
#define OFF_FINAL 0
#define OFF_PGEN  6439296
#define OFF_ATTN  6439424
#define OFF_COV   6490624
#define OFF_H1    6541824
#define OFF_C1    6607360
#define OFF_DEC   6672896

typedef __attribute__((ext_vector_type(8))) short bf16x8;
typedef __attribute__((ext_vector_type(4))) float f32x4;

static __device__ __forceinline__ float sigmoid_f(float x) {
    return 1.0f / (1.0f + __expf(-x));
}
static __device__ __forceinline__ float tanh_f(float x) {
    return 1.0f - 2.0f / (__expf(2.0f * x) + 1.0f);
}
// f32x2 -> packed bf16x2 (RNE) — v_cvt_pk_bf16_f32 on gfx950
static __device__ __forceinline__ unsigned int pk2(float x, float y) {
    union { __hip_bfloat162 h; unsigned int u; } cv;
    cv.h = __float22bfloat162_rn(make_float2(x, y));
    return cv.u;
}
static __device__ __forceinline__ unsigned short bf16_1(float x) {
    union { __hip_bfloat16 h; unsigned short u; } cv;
    cv.h = __float2bfloat16(x);
    return cv.u;
}

// Zero split-K accumulators: ws[0,393216), o_dec, w_ctx, p_gen accumulator.
__global__ __launch_bounds__(256) void zero_ws(
    float4* __restrict__ ws4, float4* __restrict__ dec4,
    float4* __restrict__ ctx4, float4* __restrict__ pga4)
{
    const int i = blockIdx.x * 256 + threadIdx.x;
    const float4 z = make_float4(0.f, 0.f, 0.f, 0.f);
    if (i < 98304) ws4[i] = z;    // w_x + w_decfea + w_gates
    if (i < 16384) dec4[i] = z;
    if (i < 16384) ctx4[i] = z;
    if (i < 32)    pga4[i] = z;
}

// ---------------------------------------------------------------------------
// Generic small GEMM: C[128 x N] (+)= A1@W1^T (+ A2@W2^T) + bias1.
// Split-K via grid.y with atomic epilogue; optional fused p_gen dot.
// ---------------------------------------------------------------------------
template <int NT>
__global__ __launch_bounds__(256) void gemm_mfma(
    const float* __restrict__ A1, const float* __restrict__ W1, int ldw1, int kwo1,
    const float* __restrict__ A2, const float* __restrict__ W2, int ldw2, int kwo2,
    const float* __restrict__ bias1,
    float* __restrict__ C, int N,
    const float* __restrict__ wpg, float* __restrict__ pgen_acc)
{
    __shared__ __align__(16) unsigned short As[128 * 40];
    __shared__ __align__(16) unsigned short Ws[NT * 16 * 40];
    const int tid  = threadIdx.x;
    const int bn0  = blockIdx.x * (NT * 16);
    const int lane = tid & 63;
    const int wv   = tid >> 6;
    const int quad = lane >> 4;
    const int col  = lane & 15;

    f32x4 acc[2][NT];
#pragma unroll
    for (int i = 0; i < 2; ++i)
#pragma unroll
        for (int j = 0; j < NT; ++j) acc[i][j] = (f32x4){0.f, 0.f, 0.f, 0.f};

    const int ar = tid >> 1;
    const int ac = (tid & 1) << 4;
    const int wr = (NT == 8) ? (tid >> 1) : (tid >> 2);
    const int wc = (NT == 8) ? ((tid & 1) << 4) : ((tid & 3) << 3);
    const int wrg = (bn0 + wr < N) ? (bn0 + wr) : (N - 1);

    const int Ktot = (A2 != nullptr) ? 1024 : 512;
    const int KC   = Ktot / gridDim.y;
    const int kg0  = blockIdx.y * KC;
    const int nsteps = KC >> 5;

    const float* ApB[2];
    const float* WpB[2];
    ApB[0] = A1 + (long)ar * 512 + ac;
    WpB[0] = W1 + (long)wrg * ldw1 + kwo1 + wc;
    ApB[1] = A2 ? (A2 + (long)ar * 512 + ac) : ApB[0];
    WpB[1] = W2 ? (W2 + (long)wrg * ldw2 + kwo2 + wc) : WpB[0];

    float4 aC[4], wC[NT / 2], aN[4], wN[NT / 2];

    auto fetch = [&](int s, float4* a, float4* w) {
        const int kg = kg0 + (s << 5);
        const int ph = kg >> 9;
        const int k0 = kg & 511;
        const float* Ap = ApB[ph] + k0;
        const float* Wp = WpB[ph] + k0;
#pragma unroll
        for (int i = 0; i < 4; ++i) a[i] = *(const float4*)(Ap + i * 4);
#pragma unroll
        for (int i = 0; i < NT / 2; ++i) w[i] = *(const float4*)(Wp + i * 4);
    };

    fetch(0, aC, wC);
    for (int s = 0; s < nsteps; ++s) {
        __syncthreads();
        uint4* apd = (uint4*)&As[ar * 40 + ac];
        apd[0] = make_uint4(pk2(aC[0].x, aC[0].y), pk2(aC[0].z, aC[0].w),
                            pk2(aC[1].x, aC[1].y), pk2(aC[1].z, aC[1].w));
        apd[1] = make_uint4(pk2(aC[2].x, aC[2].y), pk2(aC[2].z, aC[2].w),
                            pk2(aC[3].x, aC[3].y), pk2(aC[3].z, aC[3].w));
        uint4* wpd = (uint4*)&Ws[wr * 40 + wc];
        wpd[0] = make_uint4(pk2(wC[0].x, wC[0].y), pk2(wC[0].z, wC[0].w),
                            pk2(wC[1].x, wC[1].y), pk2(wC[1].z, wC[1].w));
        if (NT == 8)
            wpd[1] = make_uint4(pk2(wC[2].x, wC[2].y), pk2(wC[2].z, wC[2].w),
                                pk2(wC[3].x, wC[3].y), pk2(wC[3].z, wC[3].w));
        __syncthreads();

        if (s + 1 < nsteps) fetch(s + 1, aN, wN);

        const bf16x8 aF0 = *(const bf16x8*)&As[(wv * 32 + col) * 40 + quad * 8];
        const bf16x8 aF1 = *(const bf16x8*)&As[(wv * 32 + 16 + col) * 40 + quad * 8];
#pragma unroll
        for (int ni = 0; ni < NT; ++ni) {
            const bf16x8 bF = *(const bf16x8*)&Ws[(ni * 16 + col) * 40 + quad * 8];
            acc[0][ni] = __builtin_amdgcn_mfma_f32_16x16x32_bf16(aF0, bF, acc[0][ni], 0, 0, 0);
            acc[1][ni] = __builtin_amdgcn_mfma_f32_16x16x32_bf16(aF1, bF, acc[1][ni], 0, 0, 0);
        }
#pragma unroll
        for (int i = 0; i < 4; ++i) aC[i] = aN[i];
#pragma unroll
        for (int i = 0; i < NT / 2; ++i) wC[i] = wN[i];
    }

    const bool split = (gridDim.y > 1);
    const bool addb  = (!split) || (blockIdx.y == 0);

    float pgp[2][4];
#pragma unroll
    for (int i = 0; i < 2; ++i)
#pragma unroll
        for (int r = 0; r < 4; ++r) pgp[i][r] = 0.f;

#pragma unroll
    for (int mi = 0; mi < 2; ++mi) {
#pragma unroll
        for (int ni = 0; ni < NT; ++ni) {
            const int n = bn0 + ni * 16 + col;
            if (n < N) {
                const float bv = addb ? bias1[n] : 0.f;
                const float wpv = wpg ? wpg[n] : 0.f;
#pragma unroll
                for (int r = 0; r < 4; ++r) {
                    const int m = wv * 32 + mi * 16 + quad * 4 + r;
                    const float v = acc[mi][ni][r] + bv;
                    if (split) atomicAdd(&C[(long)m * N + n], v);
                    else       C[(long)m * N + n] = v;
                    pgp[mi][r] += v * wpv;
                }
            }
        }
    }
    if (wpg) {
#pragma unroll
        for (int mi = 0; mi < 2; ++mi)
#pragma unroll
            for (int r = 0; r < 4; ++r) {
                float v = pgp[mi][r];
                v += __shfl_xor(v, 1); v += __shfl_xor(v, 2);
                v += __shfl_xor(v, 4); v += __shfl_xor(v, 8);
                if (col == 0) {
                    const int m = wv * 32 + mi * 16 + quad * 4 + r;
                    atomicAdd(&pgen_acc[m], v);
                }
            }
    }
}

// ---------------------------------------------------------------------------
// Pack A (= dec_out, 128x512 f32) into MFMA-fragment-ordered bf16:
// unit u = ((sl*8+mt)*4+q)*16+c  holds A[mt*16+c][sl*32+q*8 .. +8] (16B).
// ---------------------------------------------------------------------------
__global__ __launch_bounds__(256) void pack_a(
    const float* __restrict__ A, unsigned short* __restrict__ Apk)
{
    const int u  = blockIdx.x * 256 + threadIdx.x;  // 8192 units
    const int c  = u & 15;
    const int q  = (u >> 4) & 3;
    const int mt = (u >> 6) & 7;
    const int sl = u >> 9;
    const float* src = A + (long)(mt * 16 + c) * 512 + sl * 32 + q * 8;
    const float4 x = *(const float4*)src;
    const float4 y = *(const float4*)(src + 4);
    *(uint4*)(Apk + (long)u * 8) = make_uint4(pk2(x.x, x.y), pk2(x.z, x.w),
                                              pk2(y.x, y.y), pk2(y.z, y.w));
}

// ---------------------------------------------------------------------------
// Vocab GEMM v6: elogits[128 x ELD] = bf16(exp(A @ W^T + bias)), fused raw
// exp-sum partials (softmax shift-invariance; logits O(1) for this model).
// Block = 32 cols x 128 rows; 32KB LDS -> 5 blocks/CU. Wave w owns rows
// [32w,32w+32). A-fragments from packed L2-hot Apk, 4-deep prefetch.
// Epilogue restages bf16 exps through padded LDS for coalesced 32B stores.
// ---------------------------------------------------------------------------
__global__ __launch_bounds__(256, 5) void vocab_gemm(
    const unsigned short* __restrict__ Apk, const float* __restrict__ W,
    const float* __restrict__ bias, unsigned short* __restrict__ E,
    float* __restrict__ ps, int nbn)
{
    __shared__ __align__(16) unsigned short Ws[32 * 512];  // 32 KB
    const int tid  = threadIdx.x;
    const int lane = tid & 63;
    const int w    = tid >> 6;
    const int quad = lane >> 4;
    const int c    = lane & 15;
    const int nb   = blockIdx.x;
    const int N    = V_;

    // ---- stage W[nb*32 .. +32)[0..512) -> bf16 LDS, swizzled (16B gran) ----
#pragma unroll
    for (int i = 0; i < 8; ++i) {
        const int r  = i * 4 + w;                       // local row 0..31
        const int rg = (nb * 32 + r < N) ? (nb * 32 + r) : (N - 1);
        const float* src = W + (long)rg * 512 + (lane << 3);
        const float4 x = *(const float4*)src;
        const float4 y = *(const float4*)(src + 4);
        const int a16 = (r << 6) + (lane ^ (r & 7));    // 16B-unit index
        *(uint4*)&Ws[a16 << 3] = make_uint4(pk2(x.x, x.y), pk2(x.z, x.w),
                                            pk2(y.x, y.y), pk2(y.z, y.w));
    }

    f32x4 acc[2][2];   // [mi][nj]
#pragma unroll
    for (int mi = 0; mi < 2; ++mi)
#pragma unroll
        for (int nj = 0; nj < 2; ++nj) acc[mi][nj] = (f32x4){0.f, 0.f, 0.f, 0.f};

    bf16x8 aP0[2], aP1[2], aP2[2], aP3[2];
    auto loadA = [&](int sl, bf16x8* dst) {
#pragma unroll
        for (int mi = 0; mi < 2; ++mi) {
            const int u = ((sl * 8 + (w * 2 + mi)) * 4 + quad) * 16 + c;
            dst[mi] = *(const bf16x8*)(Apk + (long)u * 8);
        }
    };
    loadA(0, aP0); loadA(1, aP1); loadA(2, aP2); loadA(3, aP3);
    __syncthreads();

#pragma unroll
    for (int sl = 0; sl < 16; ++sl) {
        bf16x8* cur = ((sl & 3) == 0) ? aP0 : ((sl & 3) == 1) ? aP1
                    : ((sl & 3) == 2) ? aP2 : aP3;
        const int uk = ((sl << 2) + quad) ^ (c & 7);
        const bf16x8 bF0 = *(const bf16x8*)&Ws[((c << 6) + uk) << 3];
        const bf16x8 bF1 = *(const bf16x8*)&Ws[((((16 + c)) << 6) + uk) << 3];
        acc[0][0] = __builtin_amdgcn_mfma_f32_16x16x32_bf16(cur[0], bF0, acc[0][0], 0, 0, 0);
        acc[0][1] = __builtin_amdgcn_mfma_f32_16x16x32_bf16(cur[0], bF1, acc[0][1], 0, 0, 0);
        acc[1][0] = __builtin_amdgcn_mfma_f32_16x16x32_bf16(cur[1], bF0, acc[1][0], 0, 0, 0);
        acc[1][1] = __builtin_amdgcn_mfma_f32_16x16x32_bf16(cur[1], bF1, acc[1][1], 0, 0, 0);
        if (sl + 4 < 16) loadA(sl + 4, cur);
    }

    // ---- epilogue: bf16 exps via padded LDS + in-wave per-row exp-sums ----
    __syncthreads();                       // all Ws reads done; reuse as elds
    unsigned short* elds = Ws;             // [128][34] padded (8704 ushorts)
    const int n0 = nb * 32 + c;
    const int n1 = nb * 32 + 16 + c;
    const bool ok0 = (n0 < N), ok1 = (n1 < N);
    const float bv0 = bias[ok0 ? n0 : (N - 1)];
    const float bv1 = bias[ok1 ? n1 : (N - 1)];
#pragma unroll
    for (int mi = 0; mi < 2; ++mi) {
#pragma unroll
        for (int r = 0; r < 4; ++r) {
            const int m = w * 32 + mi * 16 + quad * 4 + r;
            const float ev0 = ok0 ? __expf(acc[mi][0][r] + bv0) : 0.f;
            const float ev1 = ok1 ? __expf(acc[mi][1][r] + bv1) : 0.f;
            elds[m * 34 + c]      = bf16_1(ev0);
            elds[m * 34 + 16 + c] = bf16_1(ev1);
            float sv = ev0 + ev1;
            sv += __shfl_xor(sv, 1); sv += __shfl_xor(sv, 2);
            sv += __shfl_xor(sv, 4); sv += __shfl_xor(sv, 8);
            if (c == 0) ps[(long)m * nbn + nb] = sv;
        }
    }
    __syncthreads();
    // coalesced store: thread t -> row t>>1, 16-col half t&1 (32B vector)
    {
        const int r = tid >> 1;
        const int h = tid & 1;
        const int ncol = nb * 32 + h * 16;
        const unsigned short* src = &elds[r * 34 + h * 16];
        if (ncol + 16 <= ELD_) {
            uint4 v;
            v.x = src[0] | ((unsigned)src[1] << 16);
            v.y = src[2] | ((unsigned)src[3] << 16);
            v.z = src[4] | ((unsigned)src[5] << 16);
            v.w = src[6] | ((unsigned)src[7] << 16);
            uint4 v2;
            v2.x = src[8]  | ((unsigned)src[9] << 16);
            v2.y = src[10] | ((unsigned)src[11] << 16);
            v2.z = src[12] | ((unsigned)src[13] << 16);
            v2.w = src[14] | ((unsigned)src[15] << 16);
            *(uint4*)&E[(long)r * ELD_ + ncol] = v;
            // second 16B belongs to same 32B half? no: one half = 16 ushorts
            // = 32B total, split across the two uint4s above: store both.
            *(uint4*)&E[(long)r * ELD_ + ncol + 8] = v2;
        } else {
            for (int j = 0; j < 16; ++j) {
                const int n = ncol + j;
                if (n < N) E[(long)r * ELD_ + n] = src[j];
            }
        }
    }
}

// Merge exp-sum partials -> Srow; compute + write p_gen. grid = 128 rows.
__global__ __launch_bounds__(256) void row_merge(
    const float* __restrict__ ps, int nblk,
    const float* __restrict__ pgen_acc, const float* __restrict__ bpg,
    float* __restrict__ Srow, float* __restrict__ o_pgen)
{
    __shared__ float sred[4];
    const int b = blockIdx.x, tid = threadIdx.x;
    const float* psb = ps + (long)b * nblk;
    float s = 0.f;
    for (int i = tid; i < nblk; i += 256) s += psb[i];
#pragma unroll
    for (int off = 32; off > 0; off >>= 1) s += __shfl_down(s, off);
    if ((tid & 63) == 0) sred[tid >> 6] = s;
    __syncthreads();
    if (tid == 0) {
        Srow[b] = sred[0] + sred[1] + sred[2] + sred[3];
        o_pgen[b] = sigmoid_f(pgen_acc[b] + bpg[0]);
    }
}

// Elementwise LSTM cell over the accumulated gates buffer [128 x 2048]
// (i,f,g,o column-stacked). b_ih was added by the gates GEMM; add b_hh here.
__global__ __launch_bounds__(256) void lstm_cell(
    const float* __restrict__ gates, const float* __restrict__ bhh,
    const float* __restrict__ c0,
    float* __restrict__ h1, float* __restrict__ c1)
{
    const int idx = blockIdx.x * 256 + threadIdx.x;  // 65536 = 128*512
    const int m = idx >> 9;
    const int h = idx & 511;
    const float* g = gates + (long)m * 2048;
    const float iv = sigmoid_f(g[h]        + bhh[h]);
    const float fv = sigmoid_f(g[512 + h]  + bhh[512 + h]);
    const float gv = tanh_f   (g[1024 + h] + bhh[1024 + h]);
    const float ov = sigmoid_f(g[1536 + h] + bhh[1536 + h]);
    const float c = fv * c0[idx] + iv * gv;
    c1[idx] = c;
    h1[idx] = ov * tanh_f(c);
}

// e[b,s] = sum_h tanh(sf[b,s,h] + dec_fea[b,h] + wc*cov[b,s]) * v_att[h]
__global__ __launch_bounds__(256) void attn_scores(
    const float* __restrict__ sfeat, const float* __restrict__ decfea,
    const float* __restrict__ cov, const float* __restrict__ wc,
    const float* __restrict__ vatt, float* __restrict__ e)
{
    const int lane = threadIdx.x & 63;
    const int pair = blockIdx.x * 4 + (threadIdx.x >> 6);  // b*400+s
    const int b = pair / 400;
    const float cc = wc[0] * cov[pair];
    const float* sp = sfeat + ((long)pair << 9) + (lane << 3);
    const float* dp = decfea + (b << 9) + (lane << 3);
    const float* vp = vatt + (lane << 3);
    const float4 s0 = *(const float4*)sp, s1 = *(const float4*)(sp + 4);
    const float4 d0 = *(const float4*)dp, d1 = *(const float4*)(dp + 4);
    const float4 v0 = *(const float4*)vp, v1 = *(const float4*)(vp + 4);
    float acc = tanh_f(s0.x + d0.x + cc) * v0.x
              + tanh_f(s0.y + d0.y + cc) * v0.y
              + tanh_f(s0.z + d0.z + cc) * v0.z
              + tanh_f(s0.w + d0.w + cc) * v0.w
              + tanh_f(s1.x + d1.x + cc) * v1.x
              + tanh_f(s1.y + d1.y + cc) * v1.y
              + tanh_f(s1.z + d1.z + cc) * v1.z
              + tanh_f(s1.w + d1.w + cc) * v1.w;
#pragma unroll
    for (int off = 32; off > 0; off >>= 1) acc += __shfl_down(acc, off);
    if (lane == 0) e[pair] = acc;
}

// Fused masked softmax + coverage update + ctx partial accumulation.
// grid 512: block (b, chunk) recomputes row stats (L2-hot 3.2KB), writes
// attn/covnew for its 100-s chunk, accumulates ctx partial via atomicAdd.
__global__ __launch_bounds__(256) void softmax_ctx(
    const float* __restrict__ e, const float* __restrict__ mask,
    const float* __restrict__ cov, const float* __restrict__ states,
    float* __restrict__ attn, float* __restrict__ covnew,
    float* __restrict__ ctx)
{
    __shared__ float sm[4], sps[4], spms[4];
    __shared__ float s_attn[100];
    const int bx = blockIdx.x;
    const int b = bx >> 2, chunk = bx & 3;
    const int tid = threadIdx.x;

    float vals[2], msk[2];
    float m = -3.0e38f;
#pragma unroll
    for (int it = 0; it < 2; ++it) {
        const int s = tid + (it << 8);
        float mk = 0.f, v = -3.0e38f;
        if (s < 400) {
            mk = mask[b * 400 + s];
            v = (mk > 0.f) ? e[b * 400 + s] : -1.0e9f;
        }
        vals[it] = v; msk[it] = mk;
        m = fmaxf(m, v);
    }
#pragma unroll
    for (int off = 32; off > 0; off >>= 1) m = fmaxf(m, __shfl_down(m, off));
    if ((tid & 63) == 0) sm[tid >> 6] = m;
    __syncthreads();
    const float M = fmaxf(fmaxf(sm[0], sm[1]), fmaxf(sm[2], sm[3]));

    float sp = 0.f, spm = 0.f;
#pragma unroll
    for (int it = 0; it < 2; ++it) {
        const int s = tid + (it << 8);
        float pv = 0.f;
        if (s < 400) pv = __expf(vals[it] - M);
        sp += pv; spm += pv * msk[it];
    }
#pragma unroll
    for (int off = 32; off > 0; off >>= 1) {
        sp += __shfl_down(sp, off);
        spm += __shfl_down(spm, off);
    }
    if ((tid & 63) == 0) { sps[tid >> 6] = sp; spms[tid >> 6] = spm; }
    __syncthreads();
    const float SP = sps[0] + sps[1] + sps[2] + sps[3];
    const float SPM = spms[0] + spms[1] + spms[2] + spms[3];
    const float inv = 1.0f / (SPM + 1e-12f * SP);

    if (tid < 100) {
        const int s = chunk * 100 + tid;
        const float mk = mask[b * 400 + s];
        const float pv = (mk > 0.f) ? __expf(e[b * 400 + s] - M) : 0.f;
        const float a = pv * mk * inv;
        attn[b * 400 + s] = a;
        covnew[b * 400 + s] = cov[b * 400 + s] + a;
        s_attn[tid] = a;
    }
    __syncthreads();

    const int c = tid & 127;
    const int sh = tid >> 7;
    const float* base = states + (long)b * 400 * 512 + (long)chunk * 100 * 512;
    float4 acc = make_float4(0.f, 0.f, 0.f, 0.f);
    for (int i = 0; i < 50; ++i) {
        const int sl = sh + (i << 1);
        const float a = s_attn[sl];
        const float4 st = *(const float4*)(base + (long)sl * 512 + (c << 2));
        acc.x = fmaf(a, st.x, acc.x);
        acc.y = fmaf(a, st.y, acc.y);
        acc.z = fmaf(a, st.z, acc.z);
        acc.w = fmaf(a, st.w, acc.w);
    }
    float* cp = ctx + (b << 9) + (c << 2);
    atomicAdd(cp + 0, acc.x);
    atomicAdd(cp + 1, acc.y);
    atomicAdd(cp + 2, acc.z);
    atomicAdd(cp + 3, acc.w);
}

// final[b, v<V] = p_gen * elogit / S; final[b, V..VEXT) = 0.
__global__ __launch_bounds__(256) void final_write(
    const unsigned short* __restrict__ E, const float* __restrict__ Srow,
    const float* __restrict__ o_pgen, float* __restrict__ final)
{
    const int b = blockIdx.y;
    const int tid = threadIdx.x;
    const float sc = o_pgen[b] / Srow[b];
    const int v0 = (blockIdx.x * 256 + tid) << 2;
    if (v0 >= VX_) return;
    const unsigned short* row = E + (long)b * ELD_;
    float* out = final + (long)b * VX_ + v0;
    if (v0 + 4 <= V_) {
        const uint2 u = *(const uint2*)&row[v0];
        float4 o;
        o.x = __bfloat162float(*(const __hip_bfloat16*)&((const unsigned short*)&u)[0]) * sc;
        o.y = __bfloat162float(*(const __hip_bfloat16*)&((const unsigned short*)&u)[1]) * sc;
        o.z = __bfloat162float(*(const __hip_bfloat16*)&((const unsigned short*)&u)[2]) * sc;
        o.w = __bfloat162float(*(const __hip_bfloat16*)&((const unsigned short*)&u)[3]) * sc;
        *(float4*)out = o;
    } else {
#pragma unroll
        for (int j = 0; j < 4; ++j) {
            const int v = v0 + j;
            if (v < VX_)
                out[j] = (v < V_)
                    ? __bfloat162float(*(const __hip_bfloat16*)&row[v]) * sc
                    : 0.f;
        }
    }
}

// scatter-add copy distribution (after final_write)
__global__ __launch_bounds__(256) void scatter_kernel(
    const int* __restrict__ ids, const float* __restrict__ attn,
    const float* __restrict__ pgen, float* __restrict__ final)
{
    const int s = blockIdx.x * 256 + threadIdx.x;
    const int b = blockIdx.y;
    if (s < 400) {
        const float v = (1.0f - pgen[b]) * attn[b * 400 + s];
        atomicAdd(final + (long)b * VX_ + ids[b * 400 + s], v);
    }
}

extern "C" void kernel_launch(void* const* d_in, const int* in_sizes, int n_in,
                              void* d_out, int out_size, void* d_ws, size_t ws_size,
                              hipStream_t stream)
{
    const float* input_emb  = (const float*)d_in[0];
    const float* input_feed = (const float*)d_in[1];
    const float* hidden     = (const float*)d_in[2];
    const float* context    = (const float*)d_in[3];
    const float* states     = (const float*)d_in[4];
    const float* sfeat      = (const float*)d_in[5];
    const float* mask       = (const float*)d_in[6];
    const float* cov        = (const float*)d_in[7];
    const int*   src_ids    = (const int*)d_in[8];
    const float* W_ic  = (const float*)d_in[9];
    const float* b_ic  = (const float*)d_in[10];
    const float* W_ih  = (const float*)d_in[11];
    const float* W_hh  = (const float*)d_in[12];
    const float* b_ih  = (const float*)d_in[13];
    const float* b_hh  = (const float*)d_in[14];
    const float* W_dec = (const float*)d_in[15];
    const float* b_att = (const float*)d_in[16];
    const float* v_att = (const float*)d_in[17];
    const float* w_c   = (const float*)d_in[18];
    const float* W_out = (const float*)d_in[19];
    const float* b_out = (const float*)d_in[20];
    const float* W_pg  = (const float*)d_in[21];
    const float* b_pg  = (const float*)d_in[22];
    const float* W_v   = (const float*)d_in[23];
    const float* b_v   = (const float*)d_in[24];

    float* out = (float*)d_out;
    float* o_final = out + OFF_FINAL;
    float* o_pgen  = out + OFF_PGEN;
    float* o_attn  = out + OFF_ATTN;
    float* o_cov   = out + OFF_COV;
    float* o_h1    = out + OFF_H1;
    float* o_c1    = out + OFF_C1;
    float* o_dec   = out + OFF_DEC;

    // ws layout (floats). Early phase: w_x [0,65536) w_decfea [65536,131072)
    // w_gates [131072,393216) w_e [393344,444544) w_ctx [444544,510080).
    // Vocab phase (after those die): w_ps [0,201088).
    // Stable tail: w_elog (ushort) [510080, 510080+3216896) floats,
    // w_apk at 6942976, Srow/pga at 6975744/6976000.
    float* ws = (float*)d_ws;
    float* w_x      = ws;
    float* w_decfea = ws + 65536;
    float* w_gates  = ws + 131072;
    float* w_ps     = ws;             // reuses dead early-phase region
    float* w_e      = ws + 393344;
    float* w_ctx    = ws + 444544;
    unsigned short* w_elog = (unsigned short*)(ws + 510080);  // 128 x ELD_
    unsigned short* w_apk  = (unsigned short*)(ws + 6942976); // 128KB packed A
    float* w_Srow   = ws + 6975744;
    float* w_pga    = ws + 6976000;

    const dim3 blk(256);
    // zero split-K accumulators, o_dec, w_ctx, pga
    zero_ws<<<385, blk, 0, stream>>>((float4*)ws, (float4*)o_dec,
                                     (float4*)w_ctx, (float4*)w_pga);
    // x = [emb, feed] @ W_ic^T + b_ic   (split-K: 8 n-tiles x 8 chunks)
    gemm_mfma<4><<<dim3(8, 8), blk, 0, stream>>>(
        input_emb, W_ic, 1024, 0, input_feed, W_ic, 1024, 512,
        b_ic, w_x, 512, nullptr, nullptr);
    // gates = x @ W_ih^T + h0 @ W_hh^T + b_ih   (split-K: 32 n-tiles x 4 chunks)
    gemm_mfma<4><<<dim3(32, 4), blk, 0, stream>>>(
        w_x, W_ih, 512, 0, hidden, W_hh, 512, 0,
        b_ih, w_gates, 2048, nullptr, nullptr);
    // LSTM cell (adds b_hh) -> h1, c1
    lstm_cell<<<256, blk, 0, stream>>>(w_gates, b_hh, context, o_h1, o_c1);
    // dec_fea = h1 @ W_dec^T + b_att   (split-K: 8 x 4)
    gemm_mfma<4><<<dim3(8, 4), blk, 0, stream>>>(
        o_h1, W_dec, 512, 0, nullptr, nullptr, 0, 0,
        b_att, w_decfea, 512, nullptr, nullptr);
    // attention scores
    attn_scores<<<12800, blk, 0, stream>>>(sfeat, w_decfea, cov, w_c, v_att, w_e);
    // fused softmax + coverage + ctx
    softmax_ctx<<<512, blk, 0, stream>>>(w_e, mask, cov, states,
                                         o_attn, o_cov, w_ctx);
    // dec_out = [h1, ctx] @ W_out^T + b_out   (split-K 8 x 8, fused p_gen dot)
    gemm_mfma<4><<<dim3(8, 8), blk, 0, stream>>>(
        o_h1, W_out, 1024, 0, w_ctx, W_out, 1024, 512,
        b_out, o_dec, 512, W_pg, w_pga);
    // pack dec_out into MFMA-fragment bf16 layout (L2-resident)
    pack_a<<<32, blk, 0, stream>>>(o_dec, w_apk);
    // vocab: bf16 exp-logits + raw exp-sum partials (1571 blocks, 5/CU)
    vocab_gemm<<<NBN_, blk, 0, stream>>>(
        w_apk, W_v, b_v, w_elog, w_ps, NBN_);
    // merge exp-sums -> Srow; p_gen
    row_merge<<<128, blk, 0, stream>>>(w_ps, NBN_, w_pga, b_pg, w_Srow, o_pgen);
    // vocab dist: final = pg * elogit / S  (zeros the OOV tail)
    final_write<<<dim3(50, 128), blk, 0, stream>>>(w_elog, w_Srow,
                                                   o_pgen, o_final);
    // copy distribution scatter-add
    scatter_kernel<<<dim3(2, 128), blk, 0, stream>>>(src_ids, o_attn, o_pgen, o_final);
}